// Round 4
// baseline (574.616 us; speedup 1.0000x reference)
//
#include <hip/hip_runtime.h>
#include <math.h>

#define Bsz  64
#define Cch  2048
#define Kdim 768
#define Ssp  361
#define CPB  16                      // channels per block (sims staging)
#define REGF (CPB * Ssp)             // 5776 floats = 23104 B per block slice
#define NFULL 22                     // 22 full 1KB DMA issues ...
#define NTAIL 36                     // ... + 1 tail issue with 36 active lanes
#define NCG   (Cch / CPB)            // 128 channel groups

// ===========================================================================
// MEASUREMENT ROUND: k_sims x4, k_wts x24, k_pool x8 in-place repeats.
// Repeats are value-identical (outputs bit-equal; cross-iteration races write
// identical values). asm memory-clobber on input pointers defeats CSE so the
// loads/DMA are genuinely redone. Purpose: per-kernel attribution via
//   dur_us equation: delta = 3*t_sims + 23*t_wts + 7*t_pool
// and top-5 visibility (inflated kernels > ~115us displace the fills and
// report their own hbm_gbps / VALUBusy / Occupancy).
// ===========================================================================

// ---------------------------------------------------------------------------
// Async global->LDS DMA, 16 B per lane per issue.
// ---------------------------------------------------------------------------
__device__ __forceinline__ void dma16(const float* g, float* l) {
    __builtin_amdgcn_global_load_lds(
        (const __attribute__((address_space(1))) void*)(g),
        (__attribute__((address_space(3))) void*)(l),
        16, 0, 0);
}

// Stage one 23104 B slice (16 channels x 361 floats) into LDS; 6 waves split
// 23 issues; each wave drains its own vmcnt.
__device__ __forceinline__ void stage_slice(const float* region, float* lds,
                                            int wv, int lane) {
    for (int i = wv; i < NFULL + 1; i += 6) {
        if (i < NFULL || lane < NTAIL)
            dma16(region + i * 256 + lane * 4, lds + i * 256);
    }
    asm volatile("s_waitcnt vmcnt(0)" ::: "memory");
}

// ---------------------------------------------------------------------------
// K1: qT[c][b] = dot(text[b,:], W[c,:]) + bias[c]   (unmodified, R=1)
// ---------------------------------------------------------------------------
__global__ __launch_bounds__(256) void k_qgemm(
    const float* __restrict__ text, const float* __restrict__ W,
    const float* __restrict__ bias, float* __restrict__ qT)
{
    const int lane = threadIdx.x & 63;
    const int wv   = threadIdx.x >> 6;
    const int c0   = blockIdx.x * 8 + wv * 2;
    const int b0   = blockIdx.y * 8;

    const float4* wA = (const float4*)(W + (size_t)c0 * Kdim);
    const float4* wB = (const float4*)(W + (size_t)(c0 + 1) * Kdim);
    const float4 a0 = wA[lane*3+0], a1 = wA[lane*3+1], a2 = wA[lane*3+2];
    const float4 g0 = wB[lane*3+0], g1 = wB[lane*3+1], g2 = wB[lane*3+2];
    const float biasA = bias[c0], biasB = bias[c0 + 1];

    for (int b = b0; b < b0 + 8; b += 2) {
        const float4* tp = (const float4*)(text + (size_t)b * Kdim);
        const float4* up = (const float4*)(text + (size_t)(b + 1) * Kdim);
        const float4 t0 = tp[lane*3+0], t1 = tp[lane*3+1], t2 = tp[lane*3+2];
        const float4 u0 = up[lane*3+0], u1 = up[lane*3+1], u2 = up[lane*3+2];

        float r00 = a0.x*t0.x + a0.y*t0.y + a0.z*t0.z + a0.w*t0.w
                  + a1.x*t1.x + a1.y*t1.y + a1.z*t1.z + a1.w*t1.w
                  + a2.x*t2.x + a2.y*t2.y + a2.z*t2.z + a2.w*t2.w;
        float r10 = g0.x*t0.x + g0.y*t0.y + g0.z*t0.z + g0.w*t0.w
                  + g1.x*t1.x + g1.y*t1.y + g1.z*t1.z + g1.w*t1.w
                  + g2.x*t2.x + g2.y*t2.y + g2.z*t2.z + g2.w*t2.w;
        float r01 = a0.x*u0.x + a0.y*u0.y + a0.z*u0.z + a0.w*u0.w
                  + a1.x*u1.x + a1.y*u1.y + a1.z*u1.z + a1.w*u1.w
                  + a2.x*u2.x + a2.y*u2.y + a2.z*u2.z + a2.w*u2.w;
        float r11 = g0.x*u0.x + g0.y*u0.y + g0.z*u0.z + g0.w*u0.w
                  + g1.x*u1.x + g1.y*u1.y + g1.z*u1.z + g1.w*u1.w
                  + g2.x*u2.x + g2.y*u2.y + g2.z*u2.z + g2.w*u2.w;
        #pragma unroll
        for (int off = 32; off; off >>= 1) {
            r00 += __shfl_xor(r00, off);
            r10 += __shfl_xor(r10, off);
            r01 += __shfl_xor(r01, off);
            r11 += __shfl_xor(r11, off);
        }
        if (lane == 0) {
            qT[(size_t)c0 * Bsz + b]           = r00 + biasA;
            qT[(size_t)(c0 + 1) * Bsz + b]     = r10 + biasB;
            qT[(size_t)c0 * Bsz + b + 1]       = r01 + biasA;
            qT[(size_t)(c0 + 1) * Bsz + b + 1] = r11 + biasB;
        }
    }
}

// ---------------------------------------------------------------------------
// K2: partial sims. R=4 in-place repeats for measurement.
// ---------------------------------------------------------------------------
__global__ __launch_bounds__(384) void k_sims(
    const float* __restrict__ img, const float* __restrict__ qT,
    float* __restrict__ sims_part)
{
    const int b  = blockIdx.x;
    const int cg = blockIdx.y;
    const int tid = threadIdx.x;
    const int lane = tid & 63;
    const int wv   = tid >> 6;

    __shared__ float lds[REGF];
    __shared__ float qL[CPB];

    #pragma unroll 1
    for (int rep = 0; rep < 4; ++rep) {
        const float* img_p = img;
        const float* qT_p  = qT;
        asm volatile("" : "+v"(img_p), "+v"(qT_p) :: "memory");

        if (tid < CPB) qL[tid] = qT_p[(size_t)(cg * CPB + tid) * Bsz + b];

        const float* region = img_p + ((size_t)b * Cch + (size_t)cg * CPB) * Ssp;
        stage_slice(region, lds, wv, lane);
        __syncthreads();

        if (tid < Ssp) {
            float acc = 0.f;
            #pragma unroll
            for (int c = 0; c < CPB; c++)
                acc += qL[c] * lds[c * Ssp + tid];
            sims_part[((size_t)b * NCG + cg) * Ssp + tid] = acc;
        }
        __syncthreads();   // protect lds/qL before next repeat's staging
    }
}

// ---------------------------------------------------------------------------
// K3: weights. R=24 in-place repeats for measurement.
// ---------------------------------------------------------------------------
__global__ __launch_bounds__(384) void k_wts(
    const float* __restrict__ sims_part, float* __restrict__ wts)
{
    const int b   = blockIdx.x;
    const int tid = threadIdx.x;
    const int lane = tid & 63;
    const int wv   = tid >> 6;

    __shared__ float red[6];

    #pragma unroll 1
    for (int rep = 0; rep < 24; ++rep) {
        const float* sp_base = sims_part;
        asm volatile("" : "+v"(sp_base) :: "memory");

        float s0 = -1e30f;
        if (tid < Ssp) {
            const float* sp = sp_base + (size_t)b * NCG * Ssp + tid;
            float a = 0.f;
            for (int g0 = 0; g0 < 128; g0 += 16) {
                float v[16];
                #pragma unroll
                for (int j = 0; j < 16; j++) v[j] = sp[(size_t)(g0 + j) * Ssp];
                #pragma unroll
                for (int j = 0; j < 16; j++) a += v[j];
            }
            s0 = a;
        }

        float m = s0;
        #pragma unroll
        for (int off = 32; off; off >>= 1) m = fmaxf(m, __shfl_xor(m, off));
        if (lane == 0) red[wv] = m;
        __syncthreads();
        m = red[0];
        #pragma unroll
        for (int w = 1; w < 6; w++) m = fmaxf(m, red[w]);
        __syncthreads();

        const float e0 = (tid < Ssp) ? __expf(s0 - m) : 0.f;
        float l = e0;
        #pragma unroll
        for (int off = 32; off; off >>= 1) l += __shfl_xor(l, off);
        if (lane == 0) red[wv] = l;
        __syncthreads();
        l = red[0] + red[1] + red[2] + red[3] + red[4] + red[5];

        if (tid < Ssp)
            wts[(size_t)b * Ssp + tid] = e0 / l;
        __syncthreads();   // separate repeats (red[] reuse)
    }
}

// ---------------------------------------------------------------------------
// K4: weighted pooling, direct reads. R=8 in-place repeats for measurement.
// ---------------------------------------------------------------------------
__global__ __launch_bounds__(256) void k_pool(
    const float* __restrict__ img, const float* __restrict__ wts,
    float* __restrict__ out)
{
    const int b    = blockIdx.x;
    const int cg   = blockIdx.y;          // 16 groups x 128 channels
    const int tid  = threadIdx.x;
    const int lane = tid & 63;
    const int wv   = tid >> 6;

    __shared__ float wL[Ssp];

    #pragma unroll 1
    for (int rep = 0; rep < 8; ++rep) {
        const float* img_p = img;
        const float* wts_p = wts;
        asm volatile("" : "+v"(img_p), "+v"(wts_p) :: "memory");

        for (int s = tid; s < Ssp; s += 256)
            wL[s] = wts_p[(size_t)b * Ssp + s];
        __syncthreads();

        float wreg[6];
        #pragma unroll
        for (int k = 0; k < 6; k++) {
            const int s = lane + 64 * k;
            wreg[k] = (s < Ssp) ? wL[s] : 0.f;
        }

        const float* base = img_p + ((size_t)b * Cch + (size_t)cg * 128) * Ssp;
        const int c0 = wv * 32;

        for (int i = 0; i < 32; i += 4) {
            const float* r0 = base + (size_t)(c0 + i + 0) * Ssp;
            const float* r1 = base + (size_t)(c0 + i + 1) * Ssp;
            const float* r2 = base + (size_t)(c0 + i + 2) * Ssp;
            const float* r3 = base + (size_t)(c0 + i + 3) * Ssp;

            float a0 = 0.f, a1 = 0.f, a2 = 0.f, a3 = 0.f;
            #pragma unroll
            for (int k = 0; k < 6; k++) {
                const int s = lane + 64 * k;
                const bool ok = (s < Ssp);
                const float v0 = ok ? r0[s] : 0.f;
                const float v1 = ok ? r1[s] : 0.f;
                const float v2 = ok ? r2[s] : 0.f;
                const float v3 = ok ? r3[s] : 0.f;
                a0 += v0 * wreg[k];
                a1 += v1 * wreg[k];
                a2 += v2 * wreg[k];
                a3 += v3 * wreg[k];
            }
            #pragma unroll
            for (int off = 32; off; off >>= 1) {
                a0 += __shfl_xor(a0, off);
                a1 += __shfl_xor(a1, off);
                a2 += __shfl_xor(a2, off);
                a3 += __shfl_xor(a3, off);
            }
            if (lane == 0) {
                float* o = out + (size_t)b * Cch + (size_t)cg * 128 + c0 + i;
                o[0] = a0; o[1] = a1; o[2] = a2; o[3] = a3;
            }
        }
        __syncthreads();   // protect wL before next repeat
    }
}

// ---------------------------------------------------------------------------
extern "C" void kernel_launch(void* const* d_in, const int* in_sizes, int n_in,
                              void* d_out, int out_size, void* d_ws, size_t ws_size,
                              hipStream_t stream) {
    const float* text = (const float*)d_in[0];   // [64, 768]
    const float* img  = (const float*)d_in[1];   // [64, 2048, 19, 19]
    const float* W    = (const float*)d_in[2];   // [2048, 768]
    const float* bias = (const float*)d_in[3];   // [2048]
    float* out = (float*)d_out;                  // [64, 2048]

    // ws: qT (512 KB) + sims_part (11.8 MB) + wts (90 KB)
    float* qT        = (float*)d_ws;
    float* sims_part = qT + (size_t)Cch * Bsz;
    float* wts       = sims_part + (size_t)Bsz * NCG * Ssp;

    k_qgemm<<<dim3(256, 8),   256, 0, stream>>>(text, W, bias, qT);
    k_sims <<<dim3(Bsz, NCG), 384, 0, stream>>>(img, qT, sims_part);
    k_wts  <<<dim3(Bsz),      384, 0, stream>>>(sims_part, wts);
    k_pool <<<dim3(Bsz, 16),  256, 0, stream>>>(img, wts, out);
}

// Round 5
// 313.698 us; speedup vs baseline: 1.8318x; 1.8318x over previous
//
#include <hip/hip_runtime.h>
#include <math.h>

#define Bsz  64
#define Cch  2048
#define Kdim 768
#define Ssp  361
#define CPB  16                      // channels per block (sims staging)
#define REGF (CPB * Ssp)             // 5776 floats = 23104 B per block slice
#define NFULL 22                     // 22 full 1KB DMA issues ...
#define NTAIL 36                     // ... + 1 tail issue with 36 active lanes
#define NCG   (Cch / CPB)            // 128 channel groups

// ---------------------------------------------------------------------------
// Async global->LDS DMA, 16 B per lane per issue. DMA consumes no VGPRs, so
// the compiler cannot sink/serialize it. LDS dest: wave-uniform base + lane*16.
// ---------------------------------------------------------------------------
__device__ __forceinline__ void dma16(const float* g, float* l) {
    __builtin_amdgcn_global_load_lds(
        (const __attribute__((address_space(1))) void*)(g),
        (__attribute__((address_space(3))) void*)(l),
        16, 0, 0);
}

// ---------------------------------------------------------------------------
// K2': fused qgemm + sims. grid (b=64, cg=128) x 384.
// Issues the 23 KB img-slice DMA first, then computes the block's 16 q-values
// (16 dots of 768 vs W-slice, L2-hot) WHILE the DMA is in flight, then drains
// vmcnt and does the staged dot products. Removes the separate k_qgemm
// dispatch and its launch/drain boundary (round-4 attribution: t_qgemm ~8us
// + gap ~10us vs ~0 added here since q-compute hides under DMA latency).
// ---------------------------------------------------------------------------
__global__ __launch_bounds__(384) void k_sims(
    const float* __restrict__ text, const float* __restrict__ W,
    const float* __restrict__ bias, const float* __restrict__ img,
    float* __restrict__ sims_part)
{
    const int b  = blockIdx.x;
    const int cg = blockIdx.y;
    const int tid = threadIdx.x;
    const int lane = tid & 63;
    const int wv   = tid >> 6;

    __shared__ __align__(16) float lds[REGF];
    __shared__ float qpart[16 * 24];
    __shared__ float qL[CPB];

    // 1) issue DMA for the img slice (no drain yet)
    const float* region = img + ((size_t)b * Cch + (size_t)cg * CPB) * Ssp;
    for (int i = wv; i < NFULL + 1; i += 6) {
        if (i < NFULL || lane < NTAIL)
            dma16(region + i * 256 + lane * 4, lds + i * 256);
    }

    // 2) q-compute hidden under the DMA: 384 threads = 16 channels x 24 lanes.
    //    Thread (qc,qj): partial dot over 8 float4's (192 float4 = 768 floats).
    {
        const int qc = tid / 24;           // 0..15
        const int qj = tid - qc * 24;      // 0..23
        const float4* wr = (const float4*)(W + (size_t)(cg * CPB + qc) * Kdim);
        const float4* tr = (const float4*)(text + (size_t)b * Kdim);
        float acc = 0.f;
        #pragma unroll
        for (int t = 0; t < 8; t++) {
            const float4 w4 = wr[qj + 24 * t];
            const float4 t4 = tr[qj + 24 * t];
            acc += w4.x * t4.x + w4.y * t4.y + w4.z * t4.z + w4.w * t4.w;
        }
        qpart[qc * 24 + qj] = acc;
    }

    // 3) drain DMA (global W/text loads complete too) + barrier
    asm volatile("s_waitcnt vmcnt(0)" ::: "memory");
    __syncthreads();

    if (tid < CPB) {
        float q = bias[cg * CPB + tid];
        #pragma unroll
        for (int j = 0; j < 24; j++) q += qpart[tid * 24 + j];
        qL[tid] = q;
    }
    __syncthreads();

    // 4) staged dot products: thread s<361 does 16 conflict-free LDS reads
    if (tid < Ssp) {
        float acc = 0.f;
        #pragma unroll
        for (int c = 0; c < CPB; c++)
            acc += qL[c] * lds[c * Ssp + tid];
        sims_part[((size_t)b * NCG + cg) * Ssp + tid] = acc;
    }
}

// ---------------------------------------------------------------------------
// K3: weights. grid = 64 x 384; sums the 128 partials (L2-hot), block
// softmax, writes PRE-NORMALIZED weights. (~1-2 us, at floor — unchanged.)
// ---------------------------------------------------------------------------
__global__ __launch_bounds__(384) void k_wts(
    const float* __restrict__ sims_part, float* __restrict__ wts)
{
    const int b   = blockIdx.x;
    const int tid = threadIdx.x;
    const int lane = tid & 63;
    const int wv   = tid >> 6;

    __shared__ float red[6];

    float s0 = -1e30f;
    if (tid < Ssp) {
        const float* sp = sims_part + (size_t)b * NCG * Ssp + tid;
        float a = 0.f;
        for (int g0 = 0; g0 < 128; g0 += 16) {
            float v[16];
            #pragma unroll
            for (int j = 0; j < 16; j++) v[j] = sp[(size_t)(g0 + j) * Ssp];
            #pragma unroll
            for (int j = 0; j < 16; j++) a += v[j];
        }
        s0 = a;
    }

    float m = s0;
    #pragma unroll
    for (int off = 32; off; off >>= 1) m = fmaxf(m, __shfl_xor(m, off));
    if (lane == 0) red[wv] = m;
    __syncthreads();
    m = red[0];
    #pragma unroll
    for (int w = 1; w < 6; w++) m = fmaxf(m, red[w]);
    __syncthreads();

    const float e0 = (tid < Ssp) ? __expf(s0 - m) : 0.f;
    float l = e0;
    #pragma unroll
    for (int off = 32; off; off >>= 1) l += __shfl_xor(l, off);
    if (lane == 0) red[wv] = l;
    __syncthreads();
    l = red[0] + red[1] + red[2] + red[3] + red[4] + red[5];

    if (tid < Ssp)
        wts[(size_t)b * Ssp + tid] = e0 / l;
}

// ---------------------------------------------------------------------------
// K4: weighted pooling, direct reads. Round-4 counters: Occupancy 38%,
// hbm 45%, VALU 8% -> latency-bound with grid 1024 = 4 blocks/CU (half the
// 8-block thread cap). Fix: grid (64, 32) = 2048 blocks = exactly 8/CU.
// Wave owns 16 channels, 4-row ILP (24 loads in flight), lane = s coalesced.
// ---------------------------------------------------------------------------
__global__ __launch_bounds__(256) void k_pool(
    const float* __restrict__ img, const float* __restrict__ wts,
    float* __restrict__ out)
{
    const int b    = blockIdx.x;
    const int cg   = blockIdx.y;          // 32 groups x 64 channels
    const int tid  = threadIdx.x;
    const int lane = tid & 63;
    const int wv   = tid >> 6;

    __shared__ float wL[Ssp];
    for (int s = tid; s < Ssp; s += 256)
        wL[s] = wts[(size_t)b * Ssp + s];
    __syncthreads();

    // preload this lane's 6 weights once (s = lane + 64k), reused for all rows
    float wreg[6];
    #pragma unroll
    for (int k = 0; k < 6; k++) {
        const int s = lane + 64 * k;
        wreg[k] = (s < Ssp) ? wL[s] : 0.f;   // stride-1 lanes: conflict-free
    }

    const float* base = img + ((size_t)b * Cch + (size_t)cg * 64) * Ssp;
    const int c0 = wv * 16;                  // wave's 16 channels

    for (int i = 0; i < 16; i += 4) {
        const float* r0 = base + (size_t)(c0 + i + 0) * Ssp;
        const float* r1 = base + (size_t)(c0 + i + 1) * Ssp;
        const float* r2 = base + (size_t)(c0 + i + 2) * Ssp;
        const float* r3 = base + (size_t)(c0 + i + 3) * Ssp;

        float a0 = 0.f, a1 = 0.f, a2 = 0.f, a3 = 0.f;
        #pragma unroll
        for (int k = 0; k < 6; k++) {
            const int s = lane + 64 * k;
            const bool ok = (s < Ssp);
            const float v0 = ok ? r0[s] : 0.f;
            const float v1 = ok ? r1[s] : 0.f;
            const float v2 = ok ? r2[s] : 0.f;
            const float v3 = ok ? r3[s] : 0.f;
            a0 += v0 * wreg[k];
            a1 += v1 * wreg[k];
            a2 += v2 * wreg[k];
            a3 += v3 * wreg[k];
        }
        #pragma unroll
        for (int off = 32; off; off >>= 1) {
            a0 += __shfl_xor(a0, off);
            a1 += __shfl_xor(a1, off);
            a2 += __shfl_xor(a2, off);
            a3 += __shfl_xor(a3, off);
        }
        if (lane == 0) {
            float* o = out + (size_t)b * Cch + (size_t)cg * 64 + c0 + i;
            o[0] = a0; o[1] = a1; o[2] = a2; o[3] = a3;
        }
    }
}

// ---------------------------------------------------------------------------
extern "C" void kernel_launch(void* const* d_in, const int* in_sizes, int n_in,
                              void* d_out, int out_size, void* d_ws, size_t ws_size,
                              hipStream_t stream) {
    const float* text = (const float*)d_in[0];   // [64, 768]
    const float* img  = (const float*)d_in[1];   // [64, 2048, 19, 19]
    const float* W    = (const float*)d_in[2];   // [2048, 768]
    const float* bias = (const float*)d_in[3];   // [2048]
    float* out = (float*)d_out;                  // [64, 2048]

    // ws: (qT slot retained for layout stability) + sims_part + wts
    float* qT        = (float*)d_ws;
    float* sims_part = qT + (size_t)Cch * Bsz;
    float* wts       = sims_part + (size_t)Bsz * NCG * Ssp;
    (void)qT;

    k_sims <<<dim3(Bsz, NCG), 384, 0, stream>>>(text, W, bias, img, sims_part);
    k_wts  <<<dim3(Bsz),      384, 0, stream>>>(sims_part, wts);
    k_pool <<<dim3(Bsz, 32),  256, 0, stream>>>(img, wts, out);
}

// Round 6
// 304.317 us; speedup vs baseline: 1.8882x; 1.0308x over previous
//
#include <hip/hip_runtime.h>
#include <math.h>

#define Bsz  64
#define Cch  2048
#define Kdim 768
#define Ssp  361
#define CPB  16                      // channels per block (sims staging)
#define REGF (CPB * Ssp)             // 5776 floats = 23104 B per block slice
#define NFULL 22                     // 22 full 1KB DMA issues ...
#define NTAIL 36                     // ... + 1 tail issue with 36 active lanes
#define NCG   (Cch / CPB)            // 128 channel groups

// ---------------------------------------------------------------------------
// Async global->LDS DMA, 16 B per lane per issue. DMA consumes no VGPRs, so
// the compiler cannot sink/serialize it. LDS dest: wave-uniform base + lane*16.
// ---------------------------------------------------------------------------
__device__ __forceinline__ void dma16(const float* g, float* l) {
    __builtin_amdgcn_global_load_lds(
        (const __attribute__((address_space(1))) void*)(g),
        (__attribute__((address_space(3))) void*)(l),
        16, 0, 0);
}

// ---------------------------------------------------------------------------
// K2': fused qgemm + sims. grid (cg=128, b=64) x 384.   <-- GRID TRANSPOSED
// Round-5 post-mortem: with grid (b, cg), XCD = id%8 = b%8, so every XCD
// streamed the whole 6 MB W through its 4 MB L2 (8x, evicting) = ~384 MB of
// L2-missing reads = ~18 us regression. Transposed: id = cg + 128*b, XCD =
// cg%8 -> each XCD owns 16 cg-slices (768 KB W, L2-RESIDENT, fetched from
// HBM once, 63 L2 hits). q-compute then hides under the img DMA for free.
// ---------------------------------------------------------------------------
__global__ __launch_bounds__(384) void k_sims(
    const float* __restrict__ text, const float* __restrict__ W,
    const float* __restrict__ bias, const float* __restrict__ img,
    float* __restrict__ sims_part)
{
    const int cg = blockIdx.x;          // fast axis -> XCD = cg % 8
    const int b  = blockIdx.y;
    const int tid = threadIdx.x;
    const int lane = tid & 63;
    const int wv   = tid >> 6;

    __shared__ __align__(16) float lds[REGF];
    __shared__ float qpart[16 * 24];
    __shared__ float qL[CPB];

    // 1) issue DMA for the img slice (no drain yet)
    const float* region = img + ((size_t)b * Cch + (size_t)cg * CPB) * Ssp;
    for (int i = wv; i < NFULL + 1; i += 6) {
        if (i < NFULL || lane < NTAIL)
            dma16(region + i * 256 + lane * 4, lds + i * 256);
    }

    // 2) q-compute hidden under the DMA: 384 threads = 16 channels x 24 lanes.
    //    Thread (qc,qj): partial dot over 8 float4's (192 float4 = 768 floats).
    //    W slice is L2-hot (see header comment).
    {
        const int qc = tid / 24;           // 0..15
        const int qj = tid - qc * 24;      // 0..23
        const float4* wr = (const float4*)(W + (size_t)(cg * CPB + qc) * Kdim);
        const float4* tr = (const float4*)(text + (size_t)b * Kdim);
        float acc = 0.f;
        #pragma unroll
        for (int t = 0; t < 8; t++) {
            const float4 w4 = wr[qj + 24 * t];
            const float4 t4 = tr[qj + 24 * t];
            acc += w4.x * t4.x + w4.y * t4.y + w4.z * t4.z + w4.w * t4.w;
        }
        qpart[qc * 24 + qj] = acc;
    }

    // 3) drain DMA (W/text VGPR loads complete too) + barrier
    asm volatile("s_waitcnt vmcnt(0)" ::: "memory");
    __syncthreads();

    if (tid < CPB) {
        float q = bias[cg * CPB + tid];
        #pragma unroll
        for (int j = 0; j < 24; j++) q += qpart[tid * 24 + j];
        qL[tid] = q;
    }
    __syncthreads();

    // 4) staged dot products: thread s<361 does 16 conflict-free LDS reads
    if (tid < Ssp) {
        float acc = 0.f;
        #pragma unroll
        for (int c = 0; c < CPB; c++)
            acc += qL[c] * lds[c * Ssp + tid];
        sims_part[((size_t)b * NCG + cg) * Ssp + tid] = acc;
    }
}

// ---------------------------------------------------------------------------
// K3: weights. grid = 64 x 384; sums the 128 partials (L2-hot), block
// softmax, writes PRE-NORMALIZED weights. (~1-2 us, at floor — unchanged.)
// ---------------------------------------------------------------------------
__global__ __launch_bounds__(384) void k_wts(
    const float* __restrict__ sims_part, float* __restrict__ wts)
{
    const int b   = blockIdx.x;
    const int tid = threadIdx.x;
    const int lane = tid & 63;
    const int wv   = tid >> 6;

    __shared__ float red[6];

    float s0 = -1e30f;
    if (tid < Ssp) {
        const float* sp = sims_part + (size_t)b * NCG * Ssp + tid;
        float a = 0.f;
        for (int g0 = 0; g0 < 128; g0 += 16) {
            float v[16];
            #pragma unroll
            for (int j = 0; j < 16; j++) v[j] = sp[(size_t)(g0 + j) * Ssp];
            #pragma unroll
            for (int j = 0; j < 16; j++) a += v[j];
        }
        s0 = a;
    }

    float m = s0;
    #pragma unroll
    for (int off = 32; off; off >>= 1) m = fmaxf(m, __shfl_xor(m, off));
    if (lane == 0) red[wv] = m;
    __syncthreads();
    m = red[0];
    #pragma unroll
    for (int w = 1; w < 6; w++) m = fmaxf(m, red[w]);
    __syncthreads();

    const float e0 = (tid < Ssp) ? __expf(s0 - m) : 0.f;
    float l = e0;
    #pragma unroll
    for (int off = 32; off; off >>= 1) l += __shfl_xor(l, off);
    if (lane == 0) red[wv] = l;
    __syncthreads();
    l = red[0] + red[1] + red[2] + red[3] + red[4] + red[5];

    if (tid < Ssp)
        wts[(size_t)b * Ssp + tid] = e0 / l;
}

// ---------------------------------------------------------------------------
// K4: weighted pooling, direct reads. grid (64, 32) = 2048 blocks = 8/CU
// (round-5 occupancy fix, kept). Wave owns 16 channels, 4-row ILP, lane = s.
// ---------------------------------------------------------------------------
__global__ __launch_bounds__(256) void k_pool(
    const float* __restrict__ img, const float* __restrict__ wts,
    float* __restrict__ out)
{
    const int b    = blockIdx.x;
    const int cg   = blockIdx.y;          // 32 groups x 64 channels
    const int tid  = threadIdx.x;
    const int lane = tid & 63;
    const int wv   = tid >> 6;

    __shared__ float wL[Ssp];
    for (int s = tid; s < Ssp; s += 256)
        wL[s] = wts[(size_t)b * Ssp + s];
    __syncthreads();

    // preload this lane's 6 weights once (s = lane + 64k), reused for all rows
    float wreg[6];
    #pragma unroll
    for (int k = 0; k < 6; k++) {
        const int s = lane + 64 * k;
        wreg[k] = (s < Ssp) ? wL[s] : 0.f;   // stride-1 lanes: conflict-free
    }

    const float* base = img + ((size_t)b * Cch + (size_t)cg * 64) * Ssp;
    const int c0 = wv * 16;                  // wave's 16 channels

    for (int i = 0; i < 16; i += 4) {
        const float* r0 = base + (size_t)(c0 + i + 0) * Ssp;
        const float* r1 = base + (size_t)(c0 + i + 1) * Ssp;
        const float* r2 = base + (size_t)(c0 + i + 2) * Ssp;
        const float* r3 = base + (size_t)(c0 + i + 3) * Ssp;

        float a0 = 0.f, a1 = 0.f, a2 = 0.f, a3 = 0.f;
        #pragma unroll
        for (int k = 0; k < 6; k++) {
            const int s = lane + 64 * k;
            const bool ok = (s < Ssp);
            const float v0 = ok ? r0[s] : 0.f;
            const float v1 = ok ? r1[s] : 0.f;
            const float v2 = ok ? r2[s] : 0.f;
            const float v3 = ok ? r3[s] : 0.f;
            a0 += v0 * wreg[k];
            a1 += v1 * wreg[k];
            a2 += v2 * wreg[k];
            a3 += v3 * wreg[k];
        }
        #pragma unroll
        for (int off = 32; off; off >>= 1) {
            a0 += __shfl_xor(a0, off);
            a1 += __shfl_xor(a1, off);
            a2 += __shfl_xor(a2, off);
            a3 += __shfl_xor(a3, off);
        }
        if (lane == 0) {
            float* o = out + (size_t)b * Cch + (size_t)cg * 64 + c0 + i;
            o[0] = a0; o[1] = a1; o[2] = a2; o[3] = a3;
        }
    }
}

// ---------------------------------------------------------------------------
extern "C" void kernel_launch(void* const* d_in, const int* in_sizes, int n_in,
                              void* d_out, int out_size, void* d_ws, size_t ws_size,
                              hipStream_t stream) {
    const float* text = (const float*)d_in[0];   // [64, 768]
    const float* img  = (const float*)d_in[1];   // [64, 2048, 19, 19]
    const float* W    = (const float*)d_in[2];   // [2048, 768]
    const float* bias = (const float*)d_in[3];   // [2048]
    float* out = (float*)d_out;                  // [64, 2048]

    // ws: (qT slot retained for layout stability) + sims_part + wts
    float* qT        = (float*)d_ws;
    float* sims_part = qT + (size_t)Cch * Bsz;
    float* wts       = sims_part + (size_t)Bsz * NCG * Ssp;
    (void)qT;

    k_sims <<<dim3(NCG, Bsz), 384, 0, stream>>>(text, W, bias, img, sims_part);
    k_wts  <<<dim3(Bsz),      384, 0, stream>>>(sims_part, wts);
    k_pool <<<dim3(Bsz, 32),  256, 0, stream>>>(img, wts, out);
}